// Round 12
// baseline (564.966 us; speedup 1.0000x reference)
//
#include <hip/hip_runtime.h>
#include <stdint.h>

typedef unsigned short u16;
typedef unsigned int   u32;

#define T_SEQ 2048
#define NB 2
#define NH 16
#define HD 64
#define E_DIM 1024
#define E3 3072
#define JS1 4            // j-splits pass1
#define JS2 4            // j-splits pass2
#define S2A 36           // u16 row stride for aT (bf16, K=32 PV)
#define OS2 1040         // u16 row stride for output staging

// Legacy-shape MFMA builtins have NO underscore before dtype (16x16x16f16).
#if defined(__has_builtin)
#if __has_builtin(__builtin_amdgcn_mfma_f32_16x16x16f16)
#define MIX16 1
#endif
#endif

#ifdef MIX16
#define S2D 18           // dots rows: 16 f16 + 2 pad (36 B); K=16 mix, no K-pad
#else
#define S2D 36           // dots rows: 16 bf16 + 16 zero K-pad + 4 pad (K=32 mix)
#endif

typedef float f32x4 __attribute__((ext_vector_type(4)));
typedef short s16x8 __attribute__((ext_vector_type(8)));
#ifdef MIX16
typedef _Float16 f16x4 __attribute__((ext_vector_type(4)));
#endif

__device__ __forceinline__ float b2f(u16 u) {
    union { float f; u32 i; } v; v.i = ((u32)u) << 16; return v.f;
}
__device__ __forceinline__ u16 f2b(float f) {
    union { float f; u32 i; } v; v.f = f;
    u32 x = v.i;
    return (u16)((x + 0x7FFFu + ((x >> 16) & 1u)) >> 16);
}
__device__ __forceinline__ f32x4 mfma_bf16(s16x8 a, s16x8 b, f32x4 c) {
    return __builtin_amdgcn_mfma_f32_16x16x32_bf16(a, b, c, 0, 0, 0);
}
#ifdef MIX16
__device__ __forceinline__ f32x4 mfma_f16_16(f16x4 a, f16x4 b, f32x4 c) {
    return __builtin_amdgcn_mfma_f32_16x16x16f16(a, b, c, 0, 0, 0);
}
#endif
__device__ __forceinline__ void gl_lds16(const void* g, void* l) {
    __builtin_amdgcn_global_load_lds((const __attribute__((address_space(1))) void*)g,
                                     (__attribute__((address_space(3))) void*)l, 16, 0, 0);
}

// ---------------------------------------------------------------- dtype detector
__global__ void k_detect(const u16* __restrict__ x, int* __restrict__ flag) {
    __shared__ int cnt[256];
    int tid = threadIdx.x;
    int insane = 0;
    for (int i = tid; i < 4096; i += 256) {
        u16 v = x[2 * i];
        int e = (v >> 7) & 0xFF;
        if (e >= 143 || (e > 0 && e <= 100)) insane++;
    }
    cnt[tid] = insane;
    __syncthreads();
    if (tid == 0) {
        int s = 0;
        for (int k = 0; k < 256; ++k) s += cnt[k];
        *flag = (s > 512) ? 1 : 0;   // 1 = inputs are fp32
    }
}

// ---------------------------------------------------------------- converts
__global__ void k_cvt_bf16(const void* __restrict__ src, u16* __restrict__ dst,
                           int n, const int* __restrict__ flag) {
    int i = blockIdx.x * 256 + threadIdx.x;
    bool f32 = (*flag) != 0;
    if (i < n) dst[i] = f32 ? f2b(((const float*)src)[i]) : ((const u16*)src)[i];
}

__global__ void k_cvt_small(const void* __restrict__ a, const void* __restrict__ b,
                            const void* __restrict__ c, float* __restrict__ da,
                            float* __restrict__ db, float* __restrict__ dc,
                            const int* __restrict__ flag) {
    int i = blockIdx.x * 256 + threadIdx.x;
    bool f32 = (*flag) != 0;
    if (i < 256) {
        da[i] = f32 ? ((const float*)a)[i] : b2f(((const u16*)a)[i]);
    } else if (i < 512) {
        int j = i - 256;
        db[j] = f32 ? ((const float*)b)[j] : b2f(((const u16*)b)[j]);
    } else if (i < 1536) {
        int j = i - 512;
        dc[j] = f32 ? ((const float*)c)[j] : b2f(((const u16*)c)[j]);
    }
}

// ---------------------------------------------------------------- transpose+convert w_qkv (1024x3072 -> 3072x1024 bf16)
__global__ void k_transpose(const void* __restrict__ w, u16* __restrict__ wT,
                            const int* __restrict__ flag) {
    __shared__ u16 tile[32][33];
    bool f32 = (*flag) != 0;
    int n0 = blockIdx.x * 32;
    int k0 = blockIdx.y * 32;
    int tid = threadIdx.x;
    int c = tid & 31, r4 = tid >> 5;
#pragma unroll
    for (int it = 0; it < 4; ++it) {
        int r = r4 + it * 8;
        size_t idx = (size_t)(k0 + r) * E3 + n0 + c;
        tile[r][c] = f32 ? f2b(((const float*)w)[idx]) : ((const u16*)w)[idx];
    }
    __syncthreads();
#pragma unroll
    for (int it = 0; it < 4; ++it) {
        int r = r4 + it * 8;
        wT[(size_t)(n0 + r) * E_DIM + k0 + c] = tile[c][r];
    }
}

// ---------------------------------------------------------------- QKV GEMM (m97-style): (4096x1024)@(1024x3072)
__global__ void k_qkv(const u16* __restrict__ A, const u16* __restrict__ Bm,
                      u16* __restrict__ C) {
    __shared__ __align__(16) u16 As[128 * 32];
    __shared__ __align__(16) u16 Bs[128 * 32];
    int m0 = blockIdx.x * 128, n0 = blockIdx.y * 128;
    int tid = threadIdx.x, lane = tid & 63, wv = tid >> 6;
    int q = lane >> 4, l = lane & 15;
    int wm = (wv >> 1) * 64, wn = (wv & 1) * 64;
    f32x4 acc[4][4] = {};
    int r16 = lane >> 2;
    int ccol = (lane & 3) * 8;
    for (int kc = 0; kc < 1024; kc += 32) {
#pragma unroll
        for (int j = 0; j < 4; ++j) {
            int chunk = wv * 4 + j;
            if (chunk < 8) {
                const u16* g = A + (size_t)(m0 + chunk * 16 + r16) * 1024 + kc + ccol;
                gl_lds16(g, (char*)As + chunk * 1024);
            } else {
                int ch = chunk - 8;
                const u16* g = Bm + (size_t)(n0 + ch * 16 + r16) * 1024 + kc + ccol;
                gl_lds16(g, (char*)Bs + ch * 1024);
            }
        }
        __syncthreads();
        s16x8 af[4], bf[4];
#pragma unroll
        for (int t = 0; t < 4; ++t) {
            af[t] = *(const s16x8*)(As + (wm + t * 16 + l) * 32 + q * 8);
            bf[t] = *(const s16x8*)(Bs + (wn + t * 16 + l) * 32 + q * 8);
        }
#pragma unroll
        for (int i = 0; i < 4; ++i)
#pragma unroll
            for (int j2 = 0; j2 < 4; ++j2)
                acc[i][j2] = mfma_bf16(af[i], bf[j2], acc[i][j2]);
        __syncthreads();
    }
#pragma unroll
    for (int i = 0; i < 4; ++i)
#pragma unroll
        for (int j2 = 0; j2 < 4; ++j2)
#pragma unroll
            for (int r = 0; r < 4; ++r) {
                int row = m0 + wm + i * 16 + q * 4 + r;
                int col = n0 + wn + j2 * 16 + l;
                C[(size_t)row * E3 + col] = f2b(acc[i][j2][r]);
            }
}

// ---------------------------------------------------------------- RoPE + rearrange to (B,H,T,D) / vT (B,H,D,T)
__global__ void k_rope(const u16* __restrict__ qkv, u16* __restrict__ qr,
                       u16* __restrict__ kr, u16* __restrict__ vt) {
    __shared__ u16 tile[64][66];
    int t0 = blockIdx.x * 64;
    int h = blockIdx.y, b = blockIdx.z;
    int tid = threadIdx.x;
    const float LN_TH = 9.210340371976184f / 32.0f;
    for (int src = 0; src < 3; ++src) {
        {
            int d = tid & 63, tr = tid >> 6;
#pragma unroll
            for (int it = 0; it < 16; ++it) {
                int t = tr + it * 4;
                tile[t][d] = qkv[(size_t)(b * T_SEQ + t0 + t) * E3 + src * E_DIM + h * HD + d];
            }
        }
        __syncthreads();
        if (src < 2) {
            u16* dst = (src == 0 ? qr : kr) + ((size_t)(b * NH + h) * T_SEQ) * HD;
            int d = tid & 31, tr = tid >> 5;
            float inv = __expf(-(float)d * LN_TH);
#pragma unroll
            for (int it = 0; it < 8; ++it) {
                int t = tr + it * 8;
                float ang = (float)(t0 + t) * inv;
                float sn, cs;
                __sincosf(ang, &sn, &cs);
                float x1 = b2f(tile[t][d]);
                float x2 = b2f(tile[t][d + 32]);
                dst[(size_t)(t0 + t) * HD + d]      = f2b(x1 * cs - x2 * sn);
                dst[(size_t)(t0 + t) * HD + d + 32] = f2b(x1 * sn + x2 * cs);
            }
        } else {
            int tl = tid & 63, dr = tid >> 6;
#pragma unroll
            for (int it = 0; it < 16; ++it) {
                int d = dr + it * 4;
                vt[((size_t)(b * NH + h) * HD + d) * T_SEQ + t0 + tl] = tile[tl][d];
            }
        }
        __syncthreads();
    }
}

// ---------------------------------------------------------------- pass 1: denominator partials; merged it-phases, ping-pong, 1 barrier/16j
__global__ __launch_bounds__(256, 3) void k_pass1(const u16* __restrict__ qr, const u16* __restrict__ kr,
                                                  const float* __restrict__ w_pre, float* __restrict__ lpart) {
    __shared__ __align__(16) u16 dotsb[2 * 2 * 256 * S2D];   // 2 ping-pong bufs x (2 it x 256 rows)
    int lin = blockIdx.x;
    int combo = lin & 7;
    int b = combo >> 2, js = combo & 3;
    int i0 = (lin >> 3) * 32;
    int tid = threadIdx.x, lane = tid & 63, wv = tid >> 6;
    int q = lane >> 4, l = lane & 15;
#ifndef MIX16
    {   // zero K-pad cols 16..31 of all 4x256 rows
        uint2 z = {0u, 0u};
#pragma unroll
        for (int rr = 0; rr < 4; ++rr) {
            uint2* p0 = (uint2*)(dotsb + (rr * 256 + tid) * S2D + 16);
            p0[0] = z; p0[1] = z; p0[2] = z; p0[3] = z;
        }
    }
#endif
#ifdef MIX16
    f16x4 wpre4;
#pragma unroll
    for (int jj = 0; jj < 4; ++jj)
        wpre4[jj] = (_Float16)(w_pre[l * 16 + q * 4 + jj] * 0.125f);
#else
    s16x8 wpre;
#pragma unroll
    for (int jj = 0; jj < 8; ++jj) {
        int hh = q * 8 + jj;
        wpre[jj] = (hh < 16) ? (short)f2b(w_pre[l * 16 + hh] * 0.125f) : (short)0;
    }
#endif
    s16x8 qf[2][4][2];
#pragma unroll
    for (int it = 0; it < 2; ++it)
#pragma unroll
        for (int hl = 0; hl < 4; ++hl) {
            int h = wv * 4 + hl;
            const u16* ptr = qr + ((size_t)(b * NH + h) * T_SEQ + i0 + it * 16 + l) * HD + q * 8;
            qf[it][hl][0] = *(const s16x8*)(ptr);
            qf[it][hl][1] = *(const s16x8*)(ptr + 32);
        }
    float lacc[2][4][4] = {};
    __syncthreads();
    int jbase = js * (T_SEQ / JS1);
    for (int jstep = 0; jstep < (T_SEQ / JS1) / 16; ++jstep) {
        int jh = jbase + jstep * 16;
        u16* dots = dotsb + (jstep & 1) * (2 * 256 * S2D);
        s16x8 kf[4][2];
#pragma unroll
        for (int hl = 0; hl < 4; ++hl) {
            int h = wv * 4 + hl;
            const u16* ptr = kr + ((size_t)(b * NH + h) * T_SEQ + jh + l) * HD + q * 8;
            kf[hl][0] = *(const s16x8*)(ptr);
            kf[hl][1] = *(const s16x8*)(ptr + 32);
        }
#pragma unroll
        for (int it = 0; it < 2; ++it) {
            f32x4 dacc[4];
#pragma unroll
            for (int hl = 0; hl < 4; ++hl) {
                f32x4 z = {};
                z = mfma_bf16(qf[it][hl][0], kf[hl][0], z);
                z = mfma_bf16(qf[it][hl][1], kf[hl][1], z);
                dacc[hl] = z;
            }
#pragma unroll
            for (int r = 0; r < 4; ++r) {
                int row = it * 256 + (q * 4 + r) * 16 + l;
#ifdef MIX16
                union { u32 u[2]; _Float16 h[4]; } pk;
                pk.h[0] = (_Float16)dacc[0][r]; pk.h[1] = (_Float16)dacc[1][r];
                pk.h[2] = (_Float16)dacc[2][r]; pk.h[3] = (_Float16)dacc[3][r];
                u32* dw = (u32*)dots;
                int wi = row * 9 + wv * 2;
                dw[wi] = pk.u[0]; dw[wi + 1] = pk.u[1];
#else
                uint2 pk;
                pk.x = (u32)f2b(dacc[0][r]) | ((u32)f2b(dacc[1][r]) << 16);
                pk.y = (u32)f2b(dacc[2][r]) | ((u32)f2b(dacc[3][r]) << 16);
                *(uint2*)(dots + row * S2D + wv * 4) = pk;
#endif
            }
        }
        __syncthreads();   // A (only barrier; ping-pong covers WAR)
#pragma unroll
        for (int it = 0; it < 2; ++it)
#pragma unroll
            for (int cl = 0; cl < 4; ++cl) {
                int c = wv * 4 + cl;
                f32x4 s = {};
#ifdef MIX16
                const u32* dr_ = (const u32*)dots;
                int ri = (it * 256 + c * 16 + l) * 9 + q * 2;
                union { u32 u[2]; f16x4 v; } b4;
                b4.u[0] = dr_[ri]; b4.u[1] = dr_[ri + 1];
                s = mfma_f16_16(wpre4, b4.v, s);
#else
                int rbase = (it * 256 + c * 16 + l) * S2D;
                union { uint2 u2[2]; s16x8 v; } bf_;
                bf_.u2[0] = *(const uint2*)(dots + rbase + q * 8);
                bf_.u2[1] = *(const uint2*)(dots + rbase + q * 8 + 4);
                s = mfma_bf16(wpre, bf_.v, s);
#endif
#pragma unroll
                for (int r = 0; r < 4; ++r)
                    lacc[it][cl][r] += __expf(fminf(s[r], 60.0f));
            }
    }
#pragma unroll
    for (int it = 0; it < 2; ++it)
#pragma unroll
        for (int cl = 0; cl < 4; ++cl)
#pragma unroll
            for (int r = 0; r < 4; ++r) {
                float pv = lacc[it][cl][r];
                pv += __shfl_xor(pv, 1);
                pv += __shfl_xor(pv, 2);
                pv += __shfl_xor(pv, 4);
                pv += __shfl_xor(pv, 8);
                if (l == 0) {
                    int g = q * 4 + r;
                    int irow = wv * 4 + cl;
                    lpart[((size_t)(combo * NH + g)) * T_SEQ + i0 + it * 16 + irow] = pv;
                }
            }
}

// ---------------------------------------------------------------- pass 2: merged it-phases, A+B per 16j (4 barriers/32j)
__global__ __launch_bounds__(256, 2) void k_pass2(const u16* __restrict__ qr, const u16* __restrict__ kr,
                                                  const u16* __restrict__ vt, const float* __restrict__ lpart,
                                                  const float* __restrict__ w_pre, const float* __restrict__ w_post,
                                                  u16* __restrict__ opart) {
    __shared__ __align__(16) u16 smem[2 * 256 * S2D + 2 * 256 * S2A];  // dots(2 it) | aT0 | aT1
    __shared__ float linv[2][16][16];
    u16* dots = smem;
    u16* aTb  = smem + 2 * 256 * S2D;
    int lin = blockIdx.x;
    int combo = lin & 7;
    int b = combo >> 2, js = combo & 3;
    int i0 = (lin >> 3) * 32;
    int tid = threadIdx.x, lane = tid & 63, wv = tid >> 6;
    int q = lane >> 4, l = lane & 15;
#ifndef MIX16
    {   // zero K-pad cols 16..31 of both it-regions
        uint2 z = {0u, 0u};
#pragma unroll
        for (int rr = 0; rr < 2; ++rr) {
            uint2* p0 = (uint2*)(dots + (rr * 256 + tid) * S2D + 16);
            p0[0] = z; p0[1] = z; p0[2] = z; p0[3] = z;
        }
    }
#endif
    {   // l = sum of 4 js partials (pass1 output), fp32
        int g = tid >> 4, il = tid & 15;
        float s0 = 0.f, s1 = 0.f;
#pragma unroll
        for (int j4 = 0; j4 < 4; ++j4) {
            const float* lp = lpart + ((size_t)((b * 4 + j4) * NH + g)) * T_SEQ + i0;
            s0 += lp[il];
            s1 += lp[16 + il];
        }
        linv[0][g][il] = 1.0f / s0;
        linv[1][g][il] = 1.0f / s1;
    }
#ifdef MIX16
    f16x4 wpre4, wpost4;
#pragma unroll
    for (int jj = 0; jj < 4; ++jj) {
        wpre4[jj]  = (_Float16)(w_pre[l * 16 + q * 4 + jj] * 0.125f);
        wpost4[jj] = (_Float16)(w_post[l * 16 + q * 4 + jj]);
    }
#else
    s16x8 wpre, wpost;
#pragma unroll
    for (int jj = 0; jj < 8; ++jj) {
        int hh = q * 8 + jj;
        wpre[jj]  = (hh < 16) ? (short)f2b(w_pre[l * 16 + hh] * 0.125f) : (short)0;
        wpost[jj] = (hh < 16) ? (short)f2b(w_post[l * 16 + hh]) : (short)0;
    }
#endif
    s16x8 qf[2][4][2];
#pragma unroll
    for (int it = 0; it < 2; ++it)
#pragma unroll
        for (int hl = 0; hl < 4; ++hl) {
            int h = wv * 4 + hl;
            const u16* ptr = qr + ((size_t)(b * NH + h) * T_SEQ + i0 + it * 16 + l) * HD + q * 8;
            qf[it][hl][0] = *(const s16x8*)(ptr);
            qf[it][hl][1] = *(const s16x8*)(ptr + 32);
        }
    f32x4 oacc[2][4][4] = {};
    __syncthreads();
    int jbase = js * (T_SEQ / JS2);
    for (int jst = 0; jst < (T_SEQ / JS2) / 32; ++jst) {
        int j0 = jbase + jst * 32;
#pragma unroll
        for (int jb = 0; jb < 2; ++jb) {
            int jh = j0 + jb * 16;
            s16x8 kf[4][2];
#pragma unroll
            for (int hl = 0; hl < 4; ++hl) {
                int h = wv * 4 + hl;
                const u16* ptr = kr + ((size_t)(b * NH + h) * T_SEQ + jh + l) * HD + q * 8;
                kf[hl][0] = *(const s16x8*)(ptr);
                kf[hl][1] = *(const s16x8*)(ptr + 32);
            }
            // -------- QK phase: both i-tiles --------
#pragma unroll
            for (int it = 0; it < 2; ++it) {
                f32x4 dacc[4];
#pragma unroll
                for (int hl = 0; hl < 4; ++hl) {
                    f32x4 z = {};
                    z = mfma_bf16(qf[it][hl][0], kf[hl][0], z);
                    z = mfma_bf16(qf[it][hl][1], kf[hl][1], z);
                    dacc[hl] = z;
                }
#pragma unroll
                for (int r = 0; r < 4; ++r) {
                    int row = it * 256 + (q * 4 + r) * 16 + l;
#ifdef MIX16
                    union { u32 u[2]; _Float16 h[4]; } pk;
                    pk.h[0] = (_Float16)dacc[0][r]; pk.h[1] = (_Float16)dacc[1][r];
                    pk.h[2] = (_Float16)dacc[2][r]; pk.h[3] = (_Float16)dacc[3][r];
                    u32* dw = (u32*)dots;
                    int wi = row * 9 + wv * 2;
                    dw[wi] = pk.u[0]; dw[wi + 1] = pk.u[1];
#else
                    uint2 pk;
                    pk.x = (u32)f2b(dacc[0][r]) | ((u32)f2b(dacc[1][r]) << 16);
                    pk.y = (u32)f2b(dacc[2][r]) | ((u32)f2b(dacc[3][r]) << 16);
                    *(uint2*)(dots + row * S2D + wv * 4) = pk;
#endif
                }
            }
            __syncthreads();   // A: dots (both it) ready
            // -------- mix phase: both i-tiles --------
#pragma unroll
            for (int it = 0; it < 2; ++it) {
                u16* aT = aTb + it * 256 * S2A;
#pragma unroll
                for (int cl = 0; cl < 4; ++cl) {
                    int c = wv * 4 + cl;
                    f32x4 s = {};
#ifdef MIX16
                    const u32* dr_ = (const u32*)dots;
                    int ri = (it * 256 + c * 16 + l) * 9 + q * 2;
                    union { u32 u[2]; f16x4 v; } b4;
                    b4.u[0] = dr_[ri]; b4.u[1] = dr_[ri + 1];
                    s = mfma_f16_16(wpre4, b4.v, s);
                    f16x4 pf;
#pragma unroll
                    for (int r = 0; r < 4; ++r)
                        pf[r] = (_Float16)(__expf(fminf(s[r], 60.0f)) * linv[it][q * 4 + r][c]);
                    f32x4 a = {};
                    a = mfma_f16_16(wpost4, pf, a);
#else
                    int rbase = (it * 256 + c * 16 + l) * S2D;
                    union { uint2 u2[2]; s16x8 v; } bf_;
                    bf_.u2[0] = *(const uint2*)(dots + rbase + q * 8);
                    bf_.u2[1] = *(const uint2*)(dots + rbase + q * 8 + 4);
                    s = mfma_bf16(wpre, bf_.v, s);
                    u32 pkx, pky;
                    {
                        u16 pu[4];
#pragma unroll
                        for (int r = 0; r < 4; ++r)
                            pu[r] = f2b(__expf(fminf(s[r], 60.0f)) * linv[it][q * 4 + r][c]);
                        pkx = (u32)pu[0] | ((u32)pu[1] << 16);
                        pky = (u32)pu[2] | ((u32)pu[3] << 16);
                    }
                    int srcA = (q & 1) * 32 + l;
                    int srcB = srcA + 16;
                    u32 x0 = (u32)__shfl((int)pkx, srcA);
                    u32 x1 = (u32)__shfl((int)pky, srcA);
                    u32 x2 = (u32)__shfl((int)pkx, srcB);
                    u32 x3 = (u32)__shfl((int)pky, srcB);
                    union { u32 u[4]; s16x8 v; } pf_;
                    bool hi = (q >= 2);
                    pf_.u[0] = hi ? 0u : x0;
                    pf_.u[1] = hi ? 0u : x1;
                    pf_.u[2] = hi ? 0u : x2;
                    pf_.u[3] = hi ? 0u : x3;
                    f32x4 a = {};
                    a = mfma_bf16(wpost, pf_.v, a);
#endif
#pragma unroll
                    for (int r = 0; r < 4; ++r)
                        aT[((q * 4 + r) * 16 + c) * S2A + jb * 16 + l] = f2b(a[r]);
                }
            }
            __syncthreads();   // B: dots reusable; jb=1's B doubles as aT-complete fence
        }
        // PV with K=32 real j; V fragment shared by both i-tiles
#pragma unroll
        for (int gl = 0; gl < 4; ++gl) {
            int gp = wv * 4 + gl;
            int ar = (gp * 16 + l) * S2A;
            union { uint2 u2[2]; s16x8 v; } af0, af1;
            af0.u2[0] = *(const uint2*)(aTb + ar + q * 8);
            af0.u2[1] = *(const uint2*)(aTb + ar + q * 8 + 4);
            af1.u2[0] = *(const uint2*)(aTb + 256 * S2A + ar + q * 8);
            af1.u2[1] = *(const uint2*)(aTb + 256 * S2A + ar + q * 8 + 4);
            const u16* vp = vt + ((size_t)(b * NH + gp) * HD) * T_SEQ + j0 + q * 8;
#pragma unroll
            for (int dt = 0; dt < 4; ++dt) {
                s16x8 bfrag = *(const s16x8*)(vp + (size_t)(dt * 16 + l) * T_SEQ);
                oacc[0][gl][dt] = mfma_bf16(af0.v, bfrag, oacc[0][gl][dt]);
                oacc[1][gl][dt] = mfma_bf16(af1.v, bfrag, oacc[1][gl][dt]);
            }
        }
        // PV reads precede next A per-wave; next aT writes happen after next A -> safe
    }
    // ---- coalesced epilogue: two 16-row rounds staged in LDS (reuse smem) ----
    size_t obase = (size_t)js * ((size_t)NB * T_SEQ * E_DIM);
#pragma unroll
    for (int it = 0; it < 2; ++it) {
        __syncthreads();
        u16* ostage = smem;
#pragma unroll
        for (int gl = 0; gl < 4; ++gl) {
            int gp = wv * 4 + gl;
#pragma unroll
            for (int dt = 0; dt < 4; ++dt)
#pragma unroll
                for (int r = 0; r < 4; ++r)
                    ostage[(q * 4 + r) * OS2 + gp * 64 + dt * 16 + l] = f2b(oacc[it][gl][dt][r]);
        }
        __syncthreads();
        int row = tid >> 4, sl = tid & 15;
        u16* gbase = opart + obase + ((size_t)(b * T_SEQ) + i0 + it * 16 + row) * E_DIM;
#pragma unroll
        for (int w = 0; w < 8; ++w) {
            uint4 v = *(const uint4*)(ostage + row * OS2 + w * 128 + sl * 8);
            *(uint4*)(gbase + w * 128 + sl * 8) = v;
        }
    }
}

// ---------------------------------------------------------------- out-proj with fused 4-partial sum:
// A = sum of 4 opart slices (fp32 add, bf16 store to LDS); B via global_load_lds
__global__ void k_outproj(const u16* __restrict__ op, const u16* __restrict__ Bm,
                          const float* __restrict__ bias, void* __restrict__ outv,
                          const int* __restrict__ flag) {
    __shared__ __align__(16) u16 As[128 * 32];
    __shared__ __align__(16) u16 Bs[128 * 32];
    bool f32 = (*flag) != 0;
    const size_t SZ = (size_t)4096 * 1024;
    int m0 = blockIdx.x * 128, n0 = blockIdx.y * 128;
    int tid = threadIdx.x, lane = tid & 63, wv = tid >> 6;
    int q = lane >> 4, l = lane & 15;
    int wm = (wv >> 1) * 64, wn = (wv & 1) * 64;
    f32x4 acc[4][4] = {};
    int r16 = lane >> 2;
    int ccol = (lane & 3) * 8;
    for (int kc = 0; kc < 1024; kc += 32) {
#pragma unroll
        for (int j = 0; j < 4; ++j) {
            int chunk = wv * 4 + j;
            if (chunk < 8) {
                size_t base = (size_t)(m0 + chunk * 16 + r16) * 1024 + kc + ccol;
                union { uint4 v; u16 h[8]; } a0, a1, a2, a3, rr;
                a0.v = *(const uint4*)(op + base);
                a1.v = *(const uint4*)(op + SZ + base);
                a2.v = *(const uint4*)(op + 2 * SZ + base);
                a3.v = *(const uint4*)(op + 3 * SZ + base);
#pragma unroll
                for (int k = 0; k < 8; ++k)
                    rr.h[k] = f2b(b2f(a0.h[k]) + b2f(a1.h[k]) + b2f(a2.h[k]) + b2f(a3.h[k]));
                *(uint4*)(As + chunk * 512 + r16 * 32 + ccol) = rr.v;
            } else {
                int ch = chunk - 8;
                const u16* g = Bm + (size_t)(n0 + ch * 16 + r16) * 1024 + kc + ccol;
                gl_lds16(g, (char*)Bs + ch * 1024);
            }
        }
        __syncthreads();
        s16x8 af[4], bf[4];
#pragma unroll
        for (int t = 0; t < 4; ++t) {
            af[t] = *(const s16x8*)(As + (wm + t * 16 + l) * 32 + q * 8);
            bf[t] = *(const s16x8*)(Bs + (wn + t * 16 + l) * 32 + q * 8);
        }
#pragma unroll
        for (int i = 0; i < 4; ++i)
#pragma unroll
            for (int j2 = 0; j2 < 4; ++j2)
                acc[i][j2] = mfma_bf16(af[i], bf[j2], acc[i][j2]);
        __syncthreads();
    }
#pragma unroll
    for (int i = 0; i < 4; ++i)
#pragma unroll
        for (int j2 = 0; j2 < 4; ++j2)
#pragma unroll
            for (int r = 0; r < 4; ++r) {
                int row = m0 + wm + i * 16 + q * 4 + r;
                int col = n0 + wn + j2 * 16 + l;
                float val = acc[i][j2][r] + bias[col];
                size_t idx = (size_t)row * E_DIM + col;
                if (f32) ((float*)outv)[idx] = val;
                else     ((u16*)outv)[idx]   = f2b(val);
            }
}

extern "C" void kernel_launch(void* const* d_in, const int* in_sizes, int n_in,
                              void* d_out, int out_size, void* d_ws, size_t ws_size,
                              hipStream_t stream) {
    (void)in_sizes; (void)n_in; (void)out_size; (void)ws_size;
    const void* x      = d_in[0];
    const void* w_qkv  = d_in[1];
    const void* w_pre  = d_in[2];
    const void* w_post = d_in[3];
    const void* w_out  = d_in[4];
    const void* b_out  = d_in[5];

    char* ws = (char*)d_ws;
    size_t off = 0;
    auto alloc = [&](size_t bytes) -> char* {
        char* p = ws + off;
        off += (bytes + 255) & ~(size_t)255;
        return p;
    };
    // region0: xb(8M) | wqkvT(6M) | qkv(24M) early; aliased by opart(32M) late
    char* region0 = alloc((size_t)(8 + 6 + 24) * 1024 * 1024);
    u16*  xb      = (u16*)region0;
    u16*  wqkvT   = (u16*)(region0 + (size_t)8 * 1024 * 1024);
    u16*  qkv     = (u16*)(region0 + (size_t)14 * 1024 * 1024);
    u16*  opart   = (u16*)region0;                              // 4 x 8 MB bf16 partials
    int*  flag    = (int*)alloc(256);
    u16*  woutb   = (u16*)alloc((size_t)1024 * 1024 * 2);
    float* wpre_c = (float*)alloc(256 * 4);
    float* wpost_c= (float*)alloc(256 * 4);
    float* bout_c = (float*)alloc(1024 * 4);
    u16*  qr      = (u16*)alloc((size_t)NB * NH * T_SEQ * HD * 2);
    u16*  kr      = (u16*)alloc((size_t)NB * NH * T_SEQ * HD * 2);
    u16*  vt      = (u16*)alloc((size_t)NB * NH * HD * T_SEQ * 2);
    float* lpart  = (float*)alloc((size_t)8 * NH * T_SEQ * 4);  // [combo][g][t]

    k_detect<<<1, 256, 0, stream>>>((const u16*)x, flag);
    k_cvt_bf16<<<16384, 256, 0, stream>>>(x, xb, 4096 * 1024, flag);
    k_cvt_bf16<<<4096, 256, 0, stream>>>(w_out, woutb, 1024 * 1024, flag);
    k_cvt_small<<<6, 256, 0, stream>>>(w_pre, w_post, b_out, wpre_c, wpost_c, bout_c, flag);
    k_transpose<<<dim3(96, 32), 256, 0, stream>>>(w_qkv, wqkvT, flag);
    k_qkv<<<dim3(32, 24), 256, 0, stream>>>(xb, wqkvT, qkv);
    k_rope<<<dim3(32, 16, 2), 256, 0, stream>>>(qkv, qr, kr, vt);
    k_pass1<<<512, 256, 0, stream>>>(qr, kr, wpre_c, lpart);
    k_pass2<<<512, 256, 0, stream>>>(qr, kr, vt, lpart, wpre_c, wpost_c, opart);
    k_outproj<<<dim3(32, 8), 256, 0, stream>>>(opart, woutb, bout_c, d_out, flag);
}

// Round 13
// 507.087 us; speedup vs baseline: 1.1141x; 1.1141x over previous
//
#include <hip/hip_runtime.h>
#include <stdint.h>

typedef unsigned short u16;
typedef unsigned int   u32;

#define T_SEQ 2048
#define NB 2
#define NH 16
#define HD 64
#define E_DIM 1024
#define E3 3072
#define JS1 4            // j-splits pass1
#define JS2 4            // j-splits pass2
#define S2A 36           // u16 row stride for aT (bf16, K=32 PV)
#define OS2 1040         // u16 row stride for output staging

// Legacy-shape MFMA builtins have NO underscore before dtype (16x16x16f16).
#if defined(__has_builtin)
#if __has_builtin(__builtin_amdgcn_mfma_f32_16x16x16f16)
#define MIX16 1
#endif
#endif

#ifdef MIX16
#define S2D 18           // dots rows: 16 f16 + 2 pad (36 B); K=16 mix, no K-pad
#else
#define S2D 36           // dots rows: 16 bf16 + 16 zero K-pad + 4 pad (K=32 mix)
#endif

typedef float f32x4 __attribute__((ext_vector_type(4)));
typedef short s16x8 __attribute__((ext_vector_type(8)));
#ifdef MIX16
typedef _Float16 f16x4 __attribute__((ext_vector_type(4)));
#endif

__device__ __forceinline__ float b2f(u16 u) {
    union { float f; u32 i; } v; v.i = ((u32)u) << 16; return v.f;
}
__device__ __forceinline__ u16 f2b(float f) {
    union { float f; u32 i; } v; v.f = f;
    u32 x = v.i;
    return (u16)((x + 0x7FFFu + ((x >> 16) & 1u)) >> 16);
}
__device__ __forceinline__ f32x4 mfma_bf16(s16x8 a, s16x8 b, f32x4 c) {
    return __builtin_amdgcn_mfma_f32_16x16x32_bf16(a, b, c, 0, 0, 0);
}
#ifdef MIX16
__device__ __forceinline__ f32x4 mfma_f16_16(f16x4 a, f16x4 b, f32x4 c) {
    return __builtin_amdgcn_mfma_f32_16x16x16f16(a, b, c, 0, 0, 0);
}
#endif
__device__ __forceinline__ void gl_lds16(const void* g, void* l) {
    __builtin_amdgcn_global_load_lds((const __attribute__((address_space(1))) void*)g,
                                     (__attribute__((address_space(3))) void*)l, 16, 0, 0);
}

// ---------------------------------------------------------------- dtype detector
__global__ void k_detect(const u16* __restrict__ x, int* __restrict__ flag) {
    __shared__ int cnt[256];
    int tid = threadIdx.x;
    int insane = 0;
    for (int i = tid; i < 4096; i += 256) {
        u16 v = x[2 * i];
        int e = (v >> 7) & 0xFF;
        if (e >= 143 || (e > 0 && e <= 100)) insane++;
    }
    cnt[tid] = insane;
    __syncthreads();
    if (tid == 0) {
        int s = 0;
        for (int k = 0; k < 256; ++k) s += cnt[k];
        *flag = (s > 512) ? 1 : 0;   // 1 = inputs are fp32
    }
}

// ---------------------------------------------------------------- converts
__global__ void k_cvt_bf16(const void* __restrict__ src, u16* __restrict__ dst,
                           int n, const int* __restrict__ flag) {
    int i = blockIdx.x * 256 + threadIdx.x;
    bool f32 = (*flag) != 0;
    if (i < n) dst[i] = f32 ? f2b(((const float*)src)[i]) : ((const u16*)src)[i];
}

__global__ void k_cvt_small(const void* __restrict__ a, const void* __restrict__ b,
                            const void* __restrict__ c, float* __restrict__ da,
                            float* __restrict__ db, float* __restrict__ dc,
                            const int* __restrict__ flag) {
    int i = blockIdx.x * 256 + threadIdx.x;
    bool f32 = (*flag) != 0;
    if (i < 256) {
        da[i] = f32 ? ((const float*)a)[i] : b2f(((const u16*)a)[i]);
    } else if (i < 512) {
        int j = i - 256;
        db[j] = f32 ? ((const float*)b)[j] : b2f(((const u16*)b)[j]);
    } else if (i < 1536) {
        int j = i - 512;
        dc[j] = f32 ? ((const float*)c)[j] : b2f(((const u16*)c)[j]);
    }
}

// ---------------------------------------------------------------- transpose+convert w_qkv (1024x3072 -> 3072x1024 bf16)
__global__ void k_transpose(const void* __restrict__ w, u16* __restrict__ wT,
                            const int* __restrict__ flag) {
    __shared__ u16 tile[32][33];
    bool f32 = (*flag) != 0;
    int n0 = blockIdx.x * 32;
    int k0 = blockIdx.y * 32;
    int tid = threadIdx.x;
    int c = tid & 31, r4 = tid >> 5;
#pragma unroll
    for (int it = 0; it < 4; ++it) {
        int r = r4 + it * 8;
        size_t idx = (size_t)(k0 + r) * E3 + n0 + c;
        tile[r][c] = f32 ? f2b(((const float*)w)[idx]) : ((const u16*)w)[idx];
    }
    __syncthreads();
#pragma unroll
    for (int it = 0; it < 4; ++it) {
        int r = r4 + it * 8;
        wT[(size_t)(n0 + r) * E_DIM + k0 + c] = tile[c][r];
    }
}

// ---------------------------------------------------------------- QKV GEMM (m97-style): (4096x1024)@(1024x3072)
__global__ void k_qkv(const u16* __restrict__ A, const u16* __restrict__ Bm,
                      u16* __restrict__ C) {
    __shared__ __align__(16) u16 As[128 * 32];
    __shared__ __align__(16) u16 Bs[128 * 32];
    int m0 = blockIdx.x * 128, n0 = blockIdx.y * 128;
    int tid = threadIdx.x, lane = tid & 63, wv = tid >> 6;
    int q = lane >> 4, l = lane & 15;
    int wm = (wv >> 1) * 64, wn = (wv & 1) * 64;
    f32x4 acc[4][4] = {};
    int r16 = lane >> 2;
    int ccol = (lane & 3) * 8;
    for (int kc = 0; kc < 1024; kc += 32) {
#pragma unroll
        for (int j = 0; j < 4; ++j) {
            int chunk = wv * 4 + j;
            if (chunk < 8) {
                const u16* g = A + (size_t)(m0 + chunk * 16 + r16) * 1024 + kc + ccol;
                gl_lds16(g, (char*)As + chunk * 1024);
            } else {
                int ch = chunk - 8;
                const u16* g = Bm + (size_t)(n0 + ch * 16 + r16) * 1024 + kc + ccol;
                gl_lds16(g, (char*)Bs + ch * 1024);
            }
        }
        __syncthreads();
        s16x8 af[4], bf[4];
#pragma unroll
        for (int t = 0; t < 4; ++t) {
            af[t] = *(const s16x8*)(As + (wm + t * 16 + l) * 32 + q * 8);
            bf[t] = *(const s16x8*)(Bs + (wn + t * 16 + l) * 32 + q * 8);
        }
#pragma unroll
        for (int i = 0; i < 4; ++i)
#pragma unroll
            for (int j2 = 0; j2 < 4; ++j2)
                acc[i][j2] = mfma_bf16(af[i], bf[j2], acc[i][j2]);
        __syncthreads();
    }
#pragma unroll
    for (int i = 0; i < 4; ++i)
#pragma unroll
        for (int j2 = 0; j2 < 4; ++j2)
#pragma unroll
            for (int r = 0; r < 4; ++r) {
                int row = m0 + wm + i * 16 + q * 4 + r;
                int col = n0 + wn + j2 * 16 + l;
                C[(size_t)row * E3 + col] = f2b(acc[i][j2][r]);
            }
}

// ---------------------------------------------------------------- RoPE + rearrange to (B,H,T,D) / vT (B,H,D,T)
__global__ void k_rope(const u16* __restrict__ qkv, u16* __restrict__ qr,
                       u16* __restrict__ kr, u16* __restrict__ vt) {
    __shared__ u16 tile[64][66];
    int t0 = blockIdx.x * 64;
    int h = blockIdx.y, b = blockIdx.z;
    int tid = threadIdx.x;
    const float LN_TH = 9.210340371976184f / 32.0f;
    for (int src = 0; src < 3; ++src) {
        {
            int d = tid & 63, tr = tid >> 6;
#pragma unroll
            for (int it = 0; it < 16; ++it) {
                int t = tr + it * 4;
                tile[t][d] = qkv[(size_t)(b * T_SEQ + t0 + t) * E3 + src * E_DIM + h * HD + d];
            }
        }
        __syncthreads();
        if (src < 2) {
            u16* dst = (src == 0 ? qr : kr) + ((size_t)(b * NH + h) * T_SEQ) * HD;
            int d = tid & 31, tr = tid >> 5;
            float inv = __expf(-(float)d * LN_TH);
#pragma unroll
            for (int it = 0; it < 8; ++it) {
                int t = tr + it * 8;
                float ang = (float)(t0 + t) * inv;
                float sn, cs;
                __sincosf(ang, &sn, &cs);
                float x1 = b2f(tile[t][d]);
                float x2 = b2f(tile[t][d + 32]);
                dst[(size_t)(t0 + t) * HD + d]      = f2b(x1 * cs - x2 * sn);
                dst[(size_t)(t0 + t) * HD + d + 32] = f2b(x1 * sn + x2 * cs);
            }
        } else {
            int tl = tid & 63, dr = tid >> 6;
#pragma unroll
            for (int it = 0; it < 16; ++it) {
                int d = dr + it * 4;
                vt[((size_t)(b * NH + h) * HD + d) * T_SEQ + t0 + tl] = tile[tl][d];
            }
        }
        __syncthreads();
    }
}

// ---------------------------------------------------------------- pass 1: softmax denominator partials lpart[combo,g,t]
// R11 rhythm: per-it sub-step, ping-pong, 1 barrier per sub-step (VERIFIED pacing)
__global__ __launch_bounds__(256, 3) void k_pass1(const u16* __restrict__ qr, const u16* __restrict__ kr,
                                                  const float* __restrict__ w_pre, float* __restrict__ lpart) {
    __shared__ __align__(16) u16 dotsb[2 * 256 * S2D];
    int lin = blockIdx.x;
    int combo = lin & 7;
    int b = combo >> 2, js = combo & 3;
    int i0 = (lin >> 3) * 32;
    int tid = threadIdx.x, lane = tid & 63, wv = tid >> 6;
    int q = lane >> 4, l = lane & 15;
#ifndef MIX16
    {   // zero K-pad cols 16..31 of both buffers
        uint2 z = {0u, 0u};
        uint2* p0 = (uint2*)(dotsb + tid * S2D + 16);
        uint2* p1 = (uint2*)(dotsb + 256 * S2D + tid * S2D + 16);
        p0[0] = z; p0[1] = z; p0[2] = z; p0[3] = z;
        p1[0] = z; p1[1] = z; p1[2] = z; p1[3] = z;
    }
#endif
#ifdef MIX16
    f16x4 wpre4;
#pragma unroll
    for (int jj = 0; jj < 4; ++jj)
        wpre4[jj] = (_Float16)(w_pre[l * 16 + q * 4 + jj] * 0.125f);
#else
    s16x8 wpre;
#pragma unroll
    for (int jj = 0; jj < 8; ++jj) {
        int hh = q * 8 + jj;
        wpre[jj] = (hh < 16) ? (short)f2b(w_pre[l * 16 + hh] * 0.125f) : (short)0;
    }
#endif
    s16x8 qf[2][4][2];
#pragma unroll
    for (int it = 0; it < 2; ++it)
#pragma unroll
        for (int hl = 0; hl < 4; ++hl) {
            int h = wv * 4 + hl;
            const u16* ptr = qr + ((size_t)(b * NH + h) * T_SEQ + i0 + it * 16 + l) * HD + q * 8;
            qf[it][hl][0] = *(const s16x8*)(ptr);
            qf[it][hl][1] = *(const s16x8*)(ptr + 32);
        }
    float lacc[2][4][4] = {};
    __syncthreads();
    int jbase = js * (T_SEQ / JS1);
    for (int jstep = 0; jstep < (T_SEQ / JS1) / 16; ++jstep) {
        int jh = jbase + jstep * 16;
        s16x8 kf[4][2];
#pragma unroll
        for (int hl = 0; hl < 4; ++hl) {
            int h = wv * 4 + hl;
            const u16* ptr = kr + ((size_t)(b * NH + h) * T_SEQ + jh + l) * HD + q * 8;
            kf[hl][0] = *(const s16x8*)(ptr);
            kf[hl][1] = *(const s16x8*)(ptr + 32);
        }
#pragma unroll
        for (int it = 0; it < 2; ++it) {
            u16* dots = dotsb + (it & 1) * 256 * S2D;   // ping-pong
            f32x4 dacc[4];
#pragma unroll
            for (int hl = 0; hl < 4; ++hl) {
                f32x4 z = {};
                z = mfma_bf16(qf[it][hl][0], kf[hl][0], z);
                z = mfma_bf16(qf[it][hl][1], kf[hl][1], z);
                dacc[hl] = z;
            }
#pragma unroll
            for (int r = 0; r < 4; ++r) {
                int row = (q * 4 + r) * 16 + l;
#ifdef MIX16
                union { u32 u[2]; _Float16 h[4]; } pk;
                pk.h[0] = (_Float16)dacc[0][r]; pk.h[1] = (_Float16)dacc[1][r];
                pk.h[2] = (_Float16)dacc[2][r]; pk.h[3] = (_Float16)dacc[3][r];
                u32* dw = (u32*)dots;
                int wi = row * 9 + wv * 2;
                dw[wi] = pk.u[0]; dw[wi + 1] = pk.u[1];
#else
                uint2 pk;
                pk.x = (u32)f2b(dacc[0][r]) | ((u32)f2b(dacc[1][r]) << 16);
                pk.y = (u32)f2b(dacc[2][r]) | ((u32)f2b(dacc[3][r]) << 16);
                *(uint2*)(dots + row * S2D + wv * 4) = pk;
#endif
            }
            __syncthreads();   // A
#pragma unroll
            for (int cl = 0; cl < 4; ++cl) {
                int c = wv * 4 + cl;
                f32x4 s = {};
#ifdef MIX16
                const u32* dr_ = (const u32*)dots;
                int ri = (c * 16 + l) * 9 + q * 2;
                union { u32 u[2]; f16x4 v; } b4;
                b4.u[0] = dr_[ri]; b4.u[1] = dr_[ri + 1];
                s = mfma_f16_16(wpre4, b4.v, s);
#else
                int rbase = (c * 16 + l) * S2D;
                union { uint2 u2[2]; s16x8 v; } bf_;
                bf_.u2[0] = *(const uint2*)(dots + rbase + q * 8);
                bf_.u2[1] = *(const uint2*)(dots + rbase + q * 8 + 4);
                s = mfma_bf16(wpre, bf_.v, s);
#endif
#pragma unroll
                for (int r = 0; r < 4; ++r)
                    lacc[it][cl][r] += __expf(fminf(s[r], 60.0f));
            }
        }
    }
#pragma unroll
    for (int it = 0; it < 2; ++it)
#pragma unroll
        for (int cl = 0; cl < 4; ++cl)
#pragma unroll
            for (int r = 0; r < 4; ++r) {
                float pv = lacc[it][cl][r];
                pv += __shfl_xor(pv, 1);
                pv += __shfl_xor(pv, 2);
                pv += __shfl_xor(pv, 4);
                pv += __shfl_xor(pv, 8);
                if (l == 0) {
                    int g = q * 4 + r;
                    int irow = wv * 4 + cl;
                    lpart[((size_t)(combo * NH + g)) * T_SEQ + i0 + it * 16 + irow] = pv;
                }
            }
}

// ---------------------------------------------------------------- pass 2: R11 rhythm (A+B per 16j sub-step — VERIFIED pacing optimum)
// MIX16: mix1 K=16 f16 from dots(f16); mix2 K=16 f16 DIRECT from p registers.
__global__ __launch_bounds__(256, 2) void k_pass2(const u16* __restrict__ qr, const u16* __restrict__ kr,
                                                  const u16* __restrict__ vt, const float* __restrict__ lpart,
                                                  const float* __restrict__ w_pre, const float* __restrict__ w_post,
                                                  u16* __restrict__ opart) {
    __shared__ __align__(16) u16 smem[256 * S2D + 2 * 256 * S2A];  // dots | aT0 | aT1; ostage reuses
    __shared__ float linv[2][16][16];
    u16* dots = smem;
    u16* aTb  = smem + 256 * S2D;
    int lin = blockIdx.x;
    int combo = lin & 7;
    int b = combo >> 2, js = combo & 3;
    int i0 = (lin >> 3) * 32;
    int tid = threadIdx.x, lane = tid & 63, wv = tid >> 6;
    int q = lane >> 4, l = lane & 15;
#ifndef MIX16
    {   // zero K-pad cols 16..31 of dots
        uint2 z = {0u, 0u};
        uint2* p0 = (uint2*)(dots + tid * S2D + 16);
        p0[0] = z; p0[1] = z; p0[2] = z; p0[3] = z;
    }
#endif
    {   // l = sum of 4 js partials (pass1 output), fp32
        int g = tid >> 4, il = tid & 15;
        float s0 = 0.f, s1 = 0.f;
#pragma unroll
        for (int j4 = 0; j4 < 4; ++j4) {
            const float* lp = lpart + ((size_t)((b * 4 + j4) * NH + g)) * T_SEQ + i0;
            s0 += lp[il];
            s1 += lp[16 + il];
        }
        linv[0][g][il] = 1.0f / s0;
        linv[1][g][il] = 1.0f / s1;
    }
#ifdef MIX16
    f16x4 wpre4, wpost4;
#pragma unroll
    for (int jj = 0; jj < 4; ++jj) {
        wpre4[jj]  = (_Float16)(w_pre[l * 16 + q * 4 + jj] * 0.125f);
        wpost4[jj] = (_Float16)(w_post[l * 16 + q * 4 + jj]);
    }
#else
    s16x8 wpre, wpost;
#pragma unroll
    for (int jj = 0; jj < 8; ++jj) {
        int hh = q * 8 + jj;
        wpre[jj]  = (hh < 16) ? (short)f2b(w_pre[l * 16 + hh] * 0.125f) : (short)0;
        wpost[jj] = (hh < 16) ? (short)f2b(w_post[l * 16 + hh]) : (short)0;
    }
#endif
    s16x8 qf[2][4][2];
#pragma unroll
    for (int it = 0; it < 2; ++it)
#pragma unroll
        for (int hl = 0; hl < 4; ++hl) {
            int h = wv * 4 + hl;
            const u16* ptr = qr + ((size_t)(b * NH + h) * T_SEQ + i0 + it * 16 + l) * HD + q * 8;
            qf[it][hl][0] = *(const s16x8*)(ptr);
            qf[it][hl][1] = *(const s16x8*)(ptr + 32);
        }
    f32x4 oacc[2][4][4] = {};
    __syncthreads();
    int jbase = js * (T_SEQ / JS2);
    for (int jst = 0; jst < (T_SEQ / JS2) / 32; ++jst) {
        int j0 = jbase + jst * 32;
#pragma unroll
        for (int jb = 0; jb < 2; ++jb) {
            int jh = j0 + jb * 16;
            s16x8 kf[4][2];
#pragma unroll
            for (int hl = 0; hl < 4; ++hl) {
                int h = wv * 4 + hl;
                const u16* ptr = kr + ((size_t)(b * NH + h) * T_SEQ + jh + l) * HD + q * 8;
                kf[hl][0] = *(const s16x8*)(ptr);
                kf[hl][1] = *(const s16x8*)(ptr + 32);
            }
#pragma unroll
            for (int it = 0; it < 2; ++it) {
                f32x4 dacc[4];
#pragma unroll
                for (int hl = 0; hl < 4; ++hl) {
                    f32x4 z = {};
                    z = mfma_bf16(qf[it][hl][0], kf[hl][0], z);
                    z = mfma_bf16(qf[it][hl][1], kf[hl][1], z);
                    dacc[hl] = z;
                }
#pragma unroll
                for (int r = 0; r < 4; ++r) {
                    int row = (q * 4 + r) * 16 + l;
#ifdef MIX16
                    union { u32 u[2]; _Float16 h[4]; } pk;
                    pk.h[0] = (_Float16)dacc[0][r]; pk.h[1] = (_Float16)dacc[1][r];
                    pk.h[2] = (_Float16)dacc[2][r]; pk.h[3] = (_Float16)dacc[3][r];
                    u32* dw = (u32*)dots;
                    int wi = row * 9 + wv * 2;
                    dw[wi] = pk.u[0]; dw[wi + 1] = pk.u[1];
#else
                    uint2 pk;
                    pk.x = (u32)f2b(dacc[0][r]) | ((u32)f2b(dacc[1][r]) << 16);
                    pk.y = (u32)f2b(dacc[2][r]) | ((u32)f2b(dacc[3][r]) << 16);
                    *(uint2*)(dots + row * S2D + wv * 4) = pk;
#endif
                }
                __syncthreads();   // A: dots ready
                u16* aT = aTb + it * 256 * S2A;
#pragma unroll
                for (int cl = 0; cl < 4; ++cl) {
                    int c = wv * 4 + cl;
                    f32x4 s = {};
#ifdef MIX16
                    const u32* dr_ = (const u32*)dots;
                    int ri = (c * 16 + l) * 9 + q * 2;
                    union { u32 u[2]; f16x4 v; } b4;
                    b4.u[0] = dr_[ri]; b4.u[1] = dr_[ri + 1];
                    s = mfma_f16_16(wpre4, b4.v, s);
                    f16x4 pf;
#pragma unroll
                    for (int r = 0; r < 4; ++r)
                        pf[r] = (_Float16)(__expf(fminf(s[r], 60.0f)) * linv[it][q * 4 + r][c]);
                    f32x4 a = {};
                    a = mfma_f16_16(wpost4, pf, a);
#else
                    int rbase = (c * 16 + l) * S2D;
                    union { uint2 u2[2]; s16x8 v; } bf_;
                    bf_.u2[0] = *(const uint2*)(dots + rbase + q * 8);
                    bf_.u2[1] = *(const uint2*)(dots + rbase + q * 8 + 4);
                    s = mfma_bf16(wpre, bf_.v, s);
                    u32 pkx, pky;
                    {
                        u16 pu[4];
#pragma unroll
                        for (int r = 0; r < 4; ++r)
                            pu[r] = f2b(__expf(fminf(s[r], 60.0f)) * linv[it][q * 4 + r][c]);
                        pkx = (u32)pu[0] | ((u32)pu[1] << 16);
                        pky = (u32)pu[2] | ((u32)pu[3] << 16);
                    }
                    int srcA = (q & 1) * 32 + l;
                    int srcB = srcA + 16;
                    u32 x0 = (u32)__shfl((int)pkx, srcA);
                    u32 x1 = (u32)__shfl((int)pky, srcA);
                    u32 x2 = (u32)__shfl((int)pkx, srcB);
                    u32 x3 = (u32)__shfl((int)pky, srcB);
                    union { u32 u[4]; s16x8 v; } pf_;
                    bool hi = (q >= 2);
                    pf_.u[0] = hi ? 0u : x0;
                    pf_.u[1] = hi ? 0u : x1;
                    pf_.u[2] = hi ? 0u : x2;
                    pf_.u[3] = hi ? 0u : x3;
                    f32x4 a = {};
                    a = mfma_bf16(wpost, pf_.v, a);
#endif
#pragma unroll
                    for (int r = 0; r < 4; ++r)
                        aT[((q * 4 + r) * 16 + c) * S2A + jb * 16 + l] = f2b(a[r]);
                }
                __syncthreads();   // B: dots reusable; last one doubles as C (aT complete)
            }
        }
        // PV with K=32 real j; V fragment shared by both i-tiles
#pragma unroll
        for (int gl = 0; gl < 4; ++gl) {
            int gp = wv * 4 + gl;
            int ar = (gp * 16 + l) * S2A;
            union { uint2 u2[2]; s16x8 v; } af0, af1;
            af0.u2[0] = *(const uint2*)(aTb + ar + q * 8);
            af0.u2[1] = *(const uint2*)(aTb + ar + q * 8 + 4);
            af1.u2[0] = *(const uint2*)(aTb + 256 * S2A + ar + q * 8);
            af1.u2[1] = *(const uint2*)(aTb + 256 * S2A + ar + q * 8 + 4);
            const u16* vp = vt + ((size_t)(b * NH + gp) * HD) * T_SEQ + j0 + q * 8;
#pragma unroll
            for (int dt = 0; dt < 4; ++dt) {
                s16x8 bfrag = *(const s16x8*)(vp + (size_t)(dt * 16 + l) * T_SEQ);
                oacc[0][gl][dt] = mfma_bf16(af0.v, bfrag, oacc[0][gl][dt]);
                oacc[1][gl][dt] = mfma_bf16(af1.v, bfrag, oacc[1][gl][dt]);
            }
        }
        // PV reads precede next A per-wave; next aT writes happen after next A -> safe
    }
    // ---- coalesced epilogue: two 16-row rounds staged in LDS (reuse smem) ----
    size_t obase = (size_t)js * ((size_t)NB * T_SEQ * E_DIM);
#pragma unroll
    for (int it = 0; it < 2; ++it) {
        __syncthreads();
        u16* ostage = smem;
#pragma unroll
        for (int gl = 0; gl < 4; ++gl) {
            int gp = wv * 4 + gl;
#pragma unroll
            for (int dt = 0; dt < 4; ++dt)
#pragma unroll
                for (int r = 0; r < 4; ++r)
                    ostage[(q * 4 + r) * OS2 + gp * 64 + dt * 16 + l] = f2b(oacc[it][gl][dt][r]);
        }
        __syncthreads();
        int row = tid >> 4, sl = tid & 15;
        u16* gbase = opart + obase + ((size_t)(b * T_SEQ) + i0 + it * 16 + row) * E_DIM;
#pragma unroll
        for (int w = 0; w < 8; ++w) {
            uint4 v = *(const uint4*)(ostage + row * OS2 + w * 128 + sl * 8);
            *(uint4*)(gbase + w * 128 + sl * 8) = v;
        }
    }
}

// ---------------------------------------------------------------- out-proj with fused 4-partial sum (validated in R12):
// A = sum of 4 opart slices (fp32 add, bf16 store to LDS); B via global_load_lds
__global__ void k_outproj(const u16* __restrict__ op, const u16* __restrict__ Bm,
                          const float* __restrict__ bias, void* __restrict__ outv,
                          const int* __restrict__ flag) {
    __shared__ __align__(16) u16 As[128 * 32];
    __shared__ __align__(16) u16 Bs[128 * 32];
    bool f32 = (*flag) != 0;
    const size_t SZ = (size_t)4096 * 1024;
    int m0 = blockIdx.x * 128, n0 = blockIdx.y * 128;
    int tid = threadIdx.x, lane = tid & 63, wv = tid >> 6;
    int q = lane >> 4, l = lane & 15;
    int wm = (wv >> 1) * 64, wn = (wv & 1) * 64;
    f32x4 acc[4][4] = {};
    int r16 = lane >> 2;
    int ccol = (lane & 3) * 8;
    for (int kc = 0; kc < 1024; kc += 32) {
#pragma unroll
        for (int j = 0; j < 4; ++j) {
            int chunk = wv * 4 + j;
            if (chunk < 8) {
                size_t base = (size_t)(m0 + chunk * 16 + r16) * 1024 + kc + ccol;
                union { uint4 v; u16 h[8]; } a0, a1, a2, a3, rr;
                a0.v = *(const uint4*)(op + base);
                a1.v = *(const uint4*)(op + SZ + base);
                a2.v = *(const uint4*)(op + 2 * SZ + base);
                a3.v = *(const uint4*)(op + 3 * SZ + base);
#pragma unroll
                for (int k = 0; k < 8; ++k)
                    rr.h[k] = f2b(b2f(a0.h[k]) + b2f(a1.h[k]) + b2f(a2.h[k]) + b2f(a3.h[k]));
                *(uint4*)(As + chunk * 512 + r16 * 32 + ccol) = rr.v;
            } else {
                int ch = chunk - 8;
                const u16* g = Bm + (size_t)(n0 + ch * 16 + r16) * 1024 + kc + ccol;
                gl_lds16(g, (char*)Bs + ch * 1024);
            }
        }
        __syncthreads();
        s16x8 af[4], bf[4];
#pragma unroll
        for (int t = 0; t < 4; ++t) {
            af[t] = *(const s16x8*)(As + (wm + t * 16 + l) * 32 + q * 8);
            bf[t] = *(const s16x8*)(Bs + (wn + t * 16 + l) * 32 + q * 8);
        }
#pragma unroll
        for (int i = 0; i < 4; ++i)
#pragma unroll
            for (int j2 = 0; j2 < 4; ++j2)
                acc[i][j2] = mfma_bf16(af[i], bf[j2], acc[i][j2]);
        __syncthreads();
    }
#pragma unroll
    for (int i = 0; i < 4; ++i)
#pragma unroll
        for (int j2 = 0; j2 < 4; ++j2)
#pragma unroll
            for (int r = 0; r < 4; ++r) {
                int row = m0 + wm + i * 16 + q * 4 + r;
                int col = n0 + wn + j2 * 16 + l;
                float val = acc[i][j2][r] + bias[col];
                size_t idx = (size_t)row * E_DIM + col;
                if (f32) ((float*)outv)[idx] = val;
                else     ((u16*)outv)[idx]   = f2b(val);
            }
}

extern "C" void kernel_launch(void* const* d_in, const int* in_sizes, int n_in,
                              void* d_out, int out_size, void* d_ws, size_t ws_size,
                              hipStream_t stream) {
    (void)in_sizes; (void)n_in; (void)out_size; (void)ws_size;
    const void* x      = d_in[0];
    const void* w_qkv  = d_in[1];
    const void* w_pre  = d_in[2];
    const void* w_post = d_in[3];
    const void* w_out  = d_in[4];
    const void* b_out  = d_in[5];

    char* ws = (char*)d_ws;
    size_t off = 0;
    auto alloc = [&](size_t bytes) -> char* {
        char* p = ws + off;
        off += (bytes + 255) & ~(size_t)255;
        return p;
    };
    // region0: xb(8M) | wqkvT(6M) | qkv(24M) early; aliased by opart(32M) late
    char* region0 = alloc((size_t)(8 + 6 + 24) * 1024 * 1024);
    u16*  xb      = (u16*)region0;
    u16*  wqkvT   = (u16*)(region0 + (size_t)8 * 1024 * 1024);
    u16*  qkv     = (u16*)(region0 + (size_t)14 * 1024 * 1024);
    u16*  opart   = (u16*)region0;                              // 4 x 8 MB bf16 partials
    int*  flag    = (int*)alloc(256);
    u16*  woutb   = (u16*)alloc((size_t)1024 * 1024 * 2);
    float* wpre_c = (float*)alloc(256 * 4);
    float* wpost_c= (float*)alloc(256 * 4);
    float* bout_c = (float*)alloc(1024 * 4);
    u16*  qr      = (u16*)alloc((size_t)NB * NH * T_SEQ * HD * 2);
    u16*  kr      = (u16*)alloc((size_t)NB * NH * T_SEQ * HD * 2);
    u16*  vt      = (u16*)alloc((size_t)NB * NH * HD * T_SEQ * 2);
    float* lpart  = (float*)alloc((size_t)8 * NH * T_SEQ * 4);  // [combo][g][t]

    k_detect<<<1, 256, 0, stream>>>((const u16*)x, flag);
    k_cvt_bf16<<<16384, 256, 0, stream>>>(x, xb, 4096 * 1024, flag);
    k_cvt_bf16<<<4096, 256, 0, stream>>>(w_out, woutb, 1024 * 1024, flag);
    k_cvt_small<<<6, 256, 0, stream>>>(w_pre, w_post, b_out, wpre_c, wpost_c, bout_c, flag);
    k_transpose<<<dim3(96, 32), 256, 0, stream>>>(w_qkv, wqkvT, flag);
    k_qkv<<<dim3(32, 24), 256, 0, stream>>>(xb, wqkvT, qkv);
    k_rope<<<dim3(32, 16, 2), 256, 0, stream>>>(qkv, qr, kr, vt);
    k_pass1<<<512, 256, 0, stream>>>(qr, kr, wpre_c, lpart);
    k_pass2<<<512, 256, 0, stream>>>(qr, kr, vt, lpart, wpre_c, wpost_c, opart);
    k_outproj<<<dim3(32, 8), 256, 0, stream>>>(opart, woutb, bout_c, d_out, flag);
}

// Round 14
// 471.751 us; speedup vs baseline: 1.1976x; 1.0749x over previous
//
#include <hip/hip_runtime.h>
#include <stdint.h>

typedef unsigned short u16;
typedef unsigned int   u32;

#define T_SEQ 2048
#define NB 2
#define NH 16
#define HD 64
#define E_DIM 1024
#define E3 3072
#define JS1 4            // j-splits pass1
#define JS2 4            // j-splits pass2
#define S2A 36           // u16 row stride for aT (bf16, K=32 PV)
#define OS2 1040         // u16 row stride for output staging

// Legacy-shape MFMA builtins have NO underscore before dtype (16x16x16f16).
#if defined(__has_builtin)
#if __has_builtin(__builtin_amdgcn_mfma_f32_16x16x16f16)
#define MIX16 1
#endif
#endif

#ifdef MIX16
#define S2D 18           // dots rows: 16 f16 + 2 pad (36 B); K=16 mix, no K-pad
#else
#define S2D 36           // dots rows: 16 bf16 + 16 zero K-pad + 4 pad (K=32 mix)
#endif

typedef float f32x4 __attribute__((ext_vector_type(4)));
typedef short s16x8 __attribute__((ext_vector_type(8)));
#ifdef MIX16
typedef _Float16 f16x4 __attribute__((ext_vector_type(4)));
#endif

__device__ __forceinline__ float b2f(u16 u) {
    union { float f; u32 i; } v; v.i = ((u32)u) << 16; return v.f;
}
__device__ __forceinline__ u16 f2b(float f) {
    union { float f; u32 i; } v; v.f = f;
    u32 x = v.i;
    return (u16)((x + 0x7FFFu + ((x >> 16) & 1u)) >> 16);
}
__device__ __forceinline__ f32x4 mfma_bf16(s16x8 a, s16x8 b, f32x4 c) {
    return __builtin_amdgcn_mfma_f32_16x16x32_bf16(a, b, c, 0, 0, 0);
}
#ifdef MIX16
__device__ __forceinline__ f32x4 mfma_f16_16(f16x4 a, f16x4 b, f32x4 c) {
    return __builtin_amdgcn_mfma_f32_16x16x16f16(a, b, c, 0, 0, 0);
}
#endif
__device__ __forceinline__ void gl_lds16(const void* g, void* l) {
    __builtin_amdgcn_global_load_lds((const __attribute__((address_space(1))) void*)g,
                                     (__attribute__((address_space(3))) void*)l, 16, 0, 0);
}

// ---------------------------------------------------------------- dtype detector
__global__ void k_detect(const u16* __restrict__ x, int* __restrict__ flag) {
    __shared__ int cnt[256];
    int tid = threadIdx.x;
    int insane = 0;
    for (int i = tid; i < 4096; i += 256) {
        u16 v = x[2 * i];
        int e = (v >> 7) & 0xFF;
        if (e >= 143 || (e > 0 && e <= 100)) insane++;
    }
    cnt[tid] = insane;
    __syncthreads();
    if (tid == 0) {
        int s = 0;
        for (int k = 0; k < 256; ++k) s += cnt[k];
        *flag = (s > 512) ? 1 : 0;   // 1 = inputs are fp32
    }
}

// ---------------------------------------------------------------- converts
__global__ void k_cvt_bf16(const void* __restrict__ src, u16* __restrict__ dst,
                           int n, const int* __restrict__ flag) {
    int i = blockIdx.x * 256 + threadIdx.x;
    bool f32 = (*flag) != 0;
    if (i < n) dst[i] = f32 ? f2b(((const float*)src)[i]) : ((const u16*)src)[i];
}

__global__ void k_cvt_small(const void* __restrict__ a, const void* __restrict__ b,
                            const void* __restrict__ c, float* __restrict__ da,
                            float* __restrict__ db, float* __restrict__ dc,
                            const int* __restrict__ flag) {
    int i = blockIdx.x * 256 + threadIdx.x;
    bool f32 = (*flag) != 0;
    if (i < 256) {
        da[i] = f32 ? ((const float*)a)[i] : b2f(((const u16*)a)[i]);
    } else if (i < 512) {
        int j = i - 256;
        db[j] = f32 ? ((const float*)b)[j] : b2f(((const u16*)b)[j]);
    } else if (i < 1536) {
        int j = i - 512;
        dc[j] = f32 ? ((const float*)c)[j] : b2f(((const u16*)c)[j]);
    }
}

// ---------------------------------------------------------------- transpose+convert w_qkv (1024x3072 -> 3072x1024 bf16)
__global__ void k_transpose(const void* __restrict__ w, u16* __restrict__ wT,
                            const int* __restrict__ flag) {
    __shared__ u16 tile[32][33];
    bool f32 = (*flag) != 0;
    int n0 = blockIdx.x * 32;
    int k0 = blockIdx.y * 32;
    int tid = threadIdx.x;
    int c = tid & 31, r4 = tid >> 5;
#pragma unroll
    for (int it = 0; it < 4; ++it) {
        int r = r4 + it * 8;
        size_t idx = (size_t)(k0 + r) * E3 + n0 + c;
        tile[r][c] = f32 ? f2b(((const float*)w)[idx]) : ((const u16*)w)[idx];
    }
    __syncthreads();
#pragma unroll
    for (int it = 0; it < 4; ++it) {
        int r = r4 + it * 8;
        wT[(size_t)(n0 + r) * E_DIM + k0 + c] = tile[c][r];
    }
}

// ---------------------------------------------------------------- QKV GEMM (m97-style): (4096x1024)@(1024x3072)
__global__ void k_qkv(const u16* __restrict__ A, const u16* __restrict__ Bm,
                      u16* __restrict__ C) {
    __shared__ __align__(16) u16 As[128 * 32];
    __shared__ __align__(16) u16 Bs[128 * 32];
    int m0 = blockIdx.x * 128, n0 = blockIdx.y * 128;
    int tid = threadIdx.x, lane = tid & 63, wv = tid >> 6;
    int q = lane >> 4, l = lane & 15;
    int wm = (wv >> 1) * 64, wn = (wv & 1) * 64;
    f32x4 acc[4][4] = {};
    int r16 = lane >> 2;
    int ccol = (lane & 3) * 8;
    for (int kc = 0; kc < 1024; kc += 32) {
#pragma unroll
        for (int j = 0; j < 4; ++j) {
            int chunk = wv * 4 + j;
            if (chunk < 8) {
                const u16* g = A + (size_t)(m0 + chunk * 16 + r16) * 1024 + kc + ccol;
                gl_lds16(g, (char*)As + chunk * 1024);
            } else {
                int ch = chunk - 8;
                const u16* g = Bm + (size_t)(n0 + ch * 16 + r16) * 1024 + kc + ccol;
                gl_lds16(g, (char*)Bs + ch * 1024);
            }
        }
        __syncthreads();
        s16x8 af[4], bf[4];
#pragma unroll
        for (int t = 0; t < 4; ++t) {
            af[t] = *(const s16x8*)(As + (wm + t * 16 + l) * 32 + q * 8);
            bf[t] = *(const s16x8*)(Bs + (wn + t * 16 + l) * 32 + q * 8);
        }
#pragma unroll
        for (int i = 0; i < 4; ++i)
#pragma unroll
            for (int j2 = 0; j2 < 4; ++j2)
                acc[i][j2] = mfma_bf16(af[i], bf[j2], acc[i][j2]);
        __syncthreads();
    }
#pragma unroll
    for (int i = 0; i < 4; ++i)
#pragma unroll
        for (int j2 = 0; j2 < 4; ++j2)
#pragma unroll
            for (int r = 0; r < 4; ++r) {
                int row = m0 + wm + i * 16 + q * 4 + r;
                int col = n0 + wn + j2 * 16 + l;
                C[(size_t)row * E3 + col] = f2b(acc[i][j2][r]);
            }
}

// ---------------------------------------------------------------- RoPE + rearrange to (B,H,T,D) / vT (B,H,D,T)
__global__ void k_rope(const u16* __restrict__ qkv, u16* __restrict__ qr,
                       u16* __restrict__ kr, u16* __restrict__ vt) {
    __shared__ u16 tile[64][66];
    int t0 = blockIdx.x * 64;
    int h = blockIdx.y, b = blockIdx.z;
    int tid = threadIdx.x;
    const float LN_TH = 9.210340371976184f / 32.0f;
    for (int src = 0; src < 3; ++src) {
        {
            int d = tid & 63, tr = tid >> 6;
#pragma unroll
            for (int it = 0; it < 16; ++it) {
                int t = tr + it * 4;
                tile[t][d] = qkv[(size_t)(b * T_SEQ + t0 + t) * E3 + src * E_DIM + h * HD + d];
            }
        }
        __syncthreads();
        if (src < 2) {
            u16* dst = (src == 0 ? qr : kr) + ((size_t)(b * NH + h) * T_SEQ) * HD;
            int d = tid & 31, tr = tid >> 5;
            float inv = __expf(-(float)d * LN_TH);
#pragma unroll
            for (int it = 0; it < 8; ++it) {
                int t = tr + it * 8;
                float ang = (float)(t0 + t) * inv;
                float sn, cs;
                __sincosf(ang, &sn, &cs);
                float x1 = b2f(tile[t][d]);
                float x2 = b2f(tile[t][d + 32]);
                dst[(size_t)(t0 + t) * HD + d]      = f2b(x1 * cs - x2 * sn);
                dst[(size_t)(t0 + t) * HD + d + 32] = f2b(x1 * sn + x2 * cs);
            }
        } else {
            int tl = tid & 63, dr = tid >> 6;
#pragma unroll
            for (int it = 0; it < 16; ++it) {
                int d = dr + it * 4;
                vt[((size_t)(b * NH + h) * HD + d) * T_SEQ + t0 + tl] = tile[tl][d];
            }
        }
        __syncthreads();
    }
}

// ---------------------------------------------------------------- pass 1: softmax denominator partials lpart[combo,g,t]
// R11 rhythm: per-it sub-step, ping-pong, 1 barrier per sub-step (VERIFIED pacing)
__global__ __launch_bounds__(256, 3) void k_pass1(const u16* __restrict__ qr, const u16* __restrict__ kr,
                                                  const float* __restrict__ w_pre, float* __restrict__ lpart) {
    __shared__ __align__(16) u16 dotsb[2 * 256 * S2D];
    int lin = blockIdx.x;
    int combo = lin & 7;
    int b = combo >> 2, js = combo & 3;
    int i0 = (lin >> 3) * 32;
    int tid = threadIdx.x, lane = tid & 63, wv = tid >> 6;
    int q = lane >> 4, l = lane & 15;
#ifndef MIX16
    {   // zero K-pad cols 16..31 of both buffers
        uint2 z = {0u, 0u};
        uint2* p0 = (uint2*)(dotsb + tid * S2D + 16);
        uint2* p1 = (uint2*)(dotsb + 256 * S2D + tid * S2D + 16);
        p0[0] = z; p0[1] = z; p0[2] = z; p0[3] = z;
        p1[0] = z; p1[1] = z; p1[2] = z; p1[3] = z;
    }
#endif
#ifdef MIX16
    f16x4 wpre4;
#pragma unroll
    for (int jj = 0; jj < 4; ++jj)
        wpre4[jj] = (_Float16)(w_pre[l * 16 + q * 4 + jj] * 0.125f);
#else
    s16x8 wpre;
#pragma unroll
    for (int jj = 0; jj < 8; ++jj) {
        int hh = q * 8 + jj;
        wpre[jj] = (hh < 16) ? (short)f2b(w_pre[l * 16 + hh] * 0.125f) : (short)0;
    }
#endif
    s16x8 qf[2][4][2];
#pragma unroll
    for (int it = 0; it < 2; ++it)
#pragma unroll
        for (int hl = 0; hl < 4; ++hl) {
            int h = wv * 4 + hl;
            const u16* ptr = qr + ((size_t)(b * NH + h) * T_SEQ + i0 + it * 16 + l) * HD + q * 8;
            qf[it][hl][0] = *(const s16x8*)(ptr);
            qf[it][hl][1] = *(const s16x8*)(ptr + 32);
        }
    float lacc[2][4][4] = {};
    __syncthreads();
    int jbase = js * (T_SEQ / JS1);
    for (int jstep = 0; jstep < (T_SEQ / JS1) / 16; ++jstep) {
        int jh = jbase + jstep * 16;
        s16x8 kf[4][2];
#pragma unroll
        for (int hl = 0; hl < 4; ++hl) {
            int h = wv * 4 + hl;
            const u16* ptr = kr + ((size_t)(b * NH + h) * T_SEQ + jh + l) * HD + q * 8;
            kf[hl][0] = *(const s16x8*)(ptr);
            kf[hl][1] = *(const s16x8*)(ptr + 32);
        }
#pragma unroll
        for (int it = 0; it < 2; ++it) {
            u16* dots = dotsb + (it & 1) * 256 * S2D;   // ping-pong
            f32x4 dacc[4];
#pragma unroll
            for (int hl = 0; hl < 4; ++hl) {
                f32x4 z = {};
                z = mfma_bf16(qf[it][hl][0], kf[hl][0], z);
                z = mfma_bf16(qf[it][hl][1], kf[hl][1], z);
                dacc[hl] = z;
            }
#pragma unroll
            for (int r = 0; r < 4; ++r) {
                int row = (q * 4 + r) * 16 + l;
#ifdef MIX16
                union { u32 u[2]; _Float16 h[4]; } pk;
                pk.h[0] = (_Float16)dacc[0][r]; pk.h[1] = (_Float16)dacc[1][r];
                pk.h[2] = (_Float16)dacc[2][r]; pk.h[3] = (_Float16)dacc[3][r];
                u32* dw = (u32*)dots;
                int wi = row * 9 + wv * 2;
                dw[wi] = pk.u[0]; dw[wi + 1] = pk.u[1];
#else
                uint2 pk;
                pk.x = (u32)f2b(dacc[0][r]) | ((u32)f2b(dacc[1][r]) << 16);
                pk.y = (u32)f2b(dacc[2][r]) | ((u32)f2b(dacc[3][r]) << 16);
                *(uint2*)(dots + row * S2D + wv * 4) = pk;
#endif
            }
            __syncthreads();   // A
#pragma unroll
            for (int cl = 0; cl < 4; ++cl) {
                int c = wv * 4 + cl;
                f32x4 s = {};
#ifdef MIX16
                const u32* dr_ = (const u32*)dots;
                int ri = (c * 16 + l) * 9 + q * 2;
                union { u32 u[2]; f16x4 v; } b4;
                b4.u[0] = dr_[ri]; b4.u[1] = dr_[ri + 1];
                s = mfma_f16_16(wpre4, b4.v, s);
#else
                int rbase = (c * 16 + l) * S2D;
                union { uint2 u2[2]; s16x8 v; } bf_;
                bf_.u2[0] = *(const uint2*)(dots + rbase + q * 8);
                bf_.u2[1] = *(const uint2*)(dots + rbase + q * 8 + 4);
                s = mfma_bf16(wpre, bf_.v, s);
#endif
#pragma unroll
                for (int r = 0; r < 4; ++r)
                    lacc[it][cl][r] += __expf(fminf(s[r], 60.0f));
            }
        }
    }
#pragma unroll
    for (int it = 0; it < 2; ++it)
#pragma unroll
        for (int cl = 0; cl < 4; ++cl)
#pragma unroll
            for (int r = 0; r < 4; ++r) {
                float pv = lacc[it][cl][r];
                pv += __shfl_xor(pv, 1);
                pv += __shfl_xor(pv, 2);
                pv += __shfl_xor(pv, 4);
                pv += __shfl_xor(pv, 8);
                if (l == 0) {
                    int g = q * 4 + r;
                    int irow = wv * 4 + cl;
                    lpart[((size_t)(combo * NH + g)) * T_SEQ + i0 + it * 16 + irow] = pv;
                }
            }
}

// ---------------------------------------------------------------- pass 2: R11 rhythm (A+B per 16j sub-step — VERIFIED pacing optimum)
// MIX16: mix1 K=16 f16 from dots(f16); mix2 K=16 f16 DIRECT from p registers.
__global__ __launch_bounds__(256, 2) void k_pass2(const u16* __restrict__ qr, const u16* __restrict__ kr,
                                                  const u16* __restrict__ vt, const float* __restrict__ lpart,
                                                  const float* __restrict__ w_pre, const float* __restrict__ w_post,
                                                  u16* __restrict__ opart) {
    __shared__ __align__(16) u16 smem[256 * S2D + 2 * 256 * S2A];  // dots | aT0 | aT1; ostage reuses
    __shared__ float linv[2][16][16];
    u16* dots = smem;
    u16* aTb  = smem + 256 * S2D;
    int lin = blockIdx.x;
    int combo = lin & 7;
    int b = combo >> 2, js = combo & 3;
    int i0 = (lin >> 3) * 32;
    int tid = threadIdx.x, lane = tid & 63, wv = tid >> 6;
    int q = lane >> 4, l = lane & 15;
#ifndef MIX16
    {   // zero K-pad cols 16..31 of dots
        uint2 z = {0u, 0u};
        uint2* p0 = (uint2*)(dots + tid * S2D + 16);
        p0[0] = z; p0[1] = z; p0[2] = z; p0[3] = z;
    }
#endif
    {   // l = sum of 4 js partials (pass1 output), fp32
        int g = tid >> 4, il = tid & 15;
        float s0 = 0.f, s1 = 0.f;
#pragma unroll
        for (int j4 = 0; j4 < 4; ++j4) {
            const float* lp = lpart + ((size_t)((b * 4 + j4) * NH + g)) * T_SEQ + i0;
            s0 += lp[il];
            s1 += lp[16 + il];
        }
        linv[0][g][il] = 1.0f / s0;
        linv[1][g][il] = 1.0f / s1;
    }
#ifdef MIX16
    f16x4 wpre4, wpost4;
#pragma unroll
    for (int jj = 0; jj < 4; ++jj) {
        wpre4[jj]  = (_Float16)(w_pre[l * 16 + q * 4 + jj] * 0.125f);
        wpost4[jj] = (_Float16)(w_post[l * 16 + q * 4 + jj]);
    }
#else
    s16x8 wpre, wpost;
#pragma unroll
    for (int jj = 0; jj < 8; ++jj) {
        int hh = q * 8 + jj;
        wpre[jj]  = (hh < 16) ? (short)f2b(w_pre[l * 16 + hh] * 0.125f) : (short)0;
        wpost[jj] = (hh < 16) ? (short)f2b(w_post[l * 16 + hh]) : (short)0;
    }
#endif
    s16x8 qf[2][4][2];
#pragma unroll
    for (int it = 0; it < 2; ++it)
#pragma unroll
        for (int hl = 0; hl < 4; ++hl) {
            int h = wv * 4 + hl;
            const u16* ptr = qr + ((size_t)(b * NH + h) * T_SEQ + i0 + it * 16 + l) * HD + q * 8;
            qf[it][hl][0] = *(const s16x8*)(ptr);
            qf[it][hl][1] = *(const s16x8*)(ptr + 32);
        }
    f32x4 oacc[2][4][4] = {};
    __syncthreads();
    int jbase = js * (T_SEQ / JS2);
    for (int jst = 0; jst < (T_SEQ / JS2) / 32; ++jst) {
        int j0 = jbase + jst * 32;
#pragma unroll
        for (int jb = 0; jb < 2; ++jb) {
            int jh = j0 + jb * 16;
            s16x8 kf[4][2];
#pragma unroll
            for (int hl = 0; hl < 4; ++hl) {
                int h = wv * 4 + hl;
                const u16* ptr = kr + ((size_t)(b * NH + h) * T_SEQ + jh + l) * HD + q * 8;
                kf[hl][0] = *(const s16x8*)(ptr);
                kf[hl][1] = *(const s16x8*)(ptr + 32);
            }
#pragma unroll
            for (int it = 0; it < 2; ++it) {
                f32x4 dacc[4];
#pragma unroll
                for (int hl = 0; hl < 4; ++hl) {
                    f32x4 z = {};
                    z = mfma_bf16(qf[it][hl][0], kf[hl][0], z);
                    z = mfma_bf16(qf[it][hl][1], kf[hl][1], z);
                    dacc[hl] = z;
                }
#pragma unroll
                for (int r = 0; r < 4; ++r) {
                    int row = (q * 4 + r) * 16 + l;
#ifdef MIX16
                    union { u32 u[2]; _Float16 h[4]; } pk;
                    pk.h[0] = (_Float16)dacc[0][r]; pk.h[1] = (_Float16)dacc[1][r];
                    pk.h[2] = (_Float16)dacc[2][r]; pk.h[3] = (_Float16)dacc[3][r];
                    u32* dw = (u32*)dots;
                    int wi = row * 9 + wv * 2;
                    dw[wi] = pk.u[0]; dw[wi + 1] = pk.u[1];
#else
                    uint2 pk;
                    pk.x = (u32)f2b(dacc[0][r]) | ((u32)f2b(dacc[1][r]) << 16);
                    pk.y = (u32)f2b(dacc[2][r]) | ((u32)f2b(dacc[3][r]) << 16);
                    *(uint2*)(dots + row * S2D + wv * 4) = pk;
#endif
                }
                __syncthreads();   // A: dots ready
                u16* aT = aTb + it * 256 * S2A;
#pragma unroll
                for (int cl = 0; cl < 4; ++cl) {
                    int c = wv * 4 + cl;
                    f32x4 s = {};
#ifdef MIX16
                    const u32* dr_ = (const u32*)dots;
                    int ri = (c * 16 + l) * 9 + q * 2;
                    union { u32 u[2]; f16x4 v; } b4;
                    b4.u[0] = dr_[ri]; b4.u[1] = dr_[ri + 1];
                    s = mfma_f16_16(wpre4, b4.v, s);
                    f16x4 pf;
#pragma unroll
                    for (int r = 0; r < 4; ++r)
                        pf[r] = (_Float16)(__expf(fminf(s[r], 60.0f)) * linv[it][q * 4 + r][c]);
                    f32x4 a = {};
                    a = mfma_f16_16(wpost4, pf, a);
#else
                    int rbase = (c * 16 + l) * S2D;
                    union { uint2 u2[2]; s16x8 v; } bf_;
                    bf_.u2[0] = *(const uint2*)(dots + rbase + q * 8);
                    bf_.u2[1] = *(const uint2*)(dots + rbase + q * 8 + 4);
                    s = mfma_bf16(wpre, bf_.v, s);
                    u32 pkx, pky;
                    {
                        u16 pu[4];
#pragma unroll
                        for (int r = 0; r < 4; ++r)
                            pu[r] = f2b(__expf(fminf(s[r], 60.0f)) * linv[it][q * 4 + r][c]);
                        pkx = (u32)pu[0] | ((u32)pu[1] << 16);
                        pky = (u32)pu[2] | ((u32)pu[3] << 16);
                    }
                    int srcA = (q & 1) * 32 + l;
                    int srcB = srcA + 16;
                    u32 x0 = (u32)__shfl((int)pkx, srcA);
                    u32 x1 = (u32)__shfl((int)pky, srcA);
                    u32 x2 = (u32)__shfl((int)pkx, srcB);
                    u32 x3 = (u32)__shfl((int)pky, srcB);
                    union { u32 u[4]; s16x8 v; } pf_;
                    bool hi = (q >= 2);
                    pf_.u[0] = hi ? 0u : x0;
                    pf_.u[1] = hi ? 0u : x1;
                    pf_.u[2] = hi ? 0u : x2;
                    pf_.u[3] = hi ? 0u : x3;
                    f32x4 a = {};
                    a = mfma_bf16(wpost, pf_.v, a);
#endif
#pragma unroll
                    for (int r = 0; r < 4; ++r)
                        aT[((q * 4 + r) * 16 + c) * S2A + jb * 16 + l] = f2b(a[r]);
                }
                __syncthreads();   // B: dots reusable; last one doubles as C (aT complete)
            }
        }
        // PV with K=32 real j; V fragment shared by both i-tiles
#pragma unroll
        for (int gl = 0; gl < 4; ++gl) {
            int gp = wv * 4 + gl;
            int ar = (gp * 16 + l) * S2A;
            union { uint2 u2[2]; s16x8 v; } af0, af1;
            af0.u2[0] = *(const uint2*)(aTb + ar + q * 8);
            af0.u2[1] = *(const uint2*)(aTb + ar + q * 8 + 4);
            af1.u2[0] = *(const uint2*)(aTb + 256 * S2A + ar + q * 8);
            af1.u2[1] = *(const uint2*)(aTb + 256 * S2A + ar + q * 8 + 4);
            const u16* vp = vt + ((size_t)(b * NH + gp) * HD) * T_SEQ + j0 + q * 8;
#pragma unroll
            for (int dt = 0; dt < 4; ++dt) {
                s16x8 bfrag = *(const s16x8*)(vp + (size_t)(dt * 16 + l) * T_SEQ);
                oacc[0][gl][dt] = mfma_bf16(af0.v, bfrag, oacc[0][gl][dt]);
                oacc[1][gl][dt] = mfma_bf16(af1.v, bfrag, oacc[1][gl][dt]);
            }
        }
        // PV reads precede next A per-wave; next aT writes happen after next A -> safe
    }
    // ---- coalesced epilogue: two 16-row rounds staged in LDS (reuse smem) ----
    size_t obase = (size_t)js * ((size_t)NB * T_SEQ * E_DIM);
#pragma unroll
    for (int it = 0; it < 2; ++it) {
        __syncthreads();
        u16* ostage = smem;
#pragma unroll
        for (int gl = 0; gl < 4; ++gl) {
            int gp = wv * 4 + gl;
#pragma unroll
            for (int dt = 0; dt < 4; ++dt)
#pragma unroll
                for (int r = 0; r < 4; ++r)
                    ostage[(q * 4 + r) * OS2 + gp * 64 + dt * 16 + l] = f2b(oacc[it][gl][dt][r]);
        }
        __syncthreads();
        int row = tid >> 4, sl = tid & 15;
        u16* gbase = opart + obase + ((size_t)(b * T_SEQ) + i0 + it * 16 + row) * E_DIM;
#pragma unroll
        for (int w = 0; w < 8; ++w) {
            uint4 v = *(const uint4*)(ostage + row * OS2 + w * 128 + sl * 8);
            *(uint4*)(gbase + w * 128 + sl * 8) = v;
        }
    }
}

// ---------------------------------------------------------------- sum 4 bf16 partials -> bf16 (one-shot; cheaper than per-n0 refusion)
__global__ void k_sum(const u16* __restrict__ op, u16* __restrict__ ab) {
    int i = (blockIdx.x * 256 + threadIdx.x) * 8;
    const size_t SZ = (size_t)4096 * 1024;
    union { uint4 v; u16 h[8]; } a0, a1, a2, a3, r;
    a0.v = *(const uint4*)(op + i);
    a1.v = *(const uint4*)(op + SZ + i);
    a2.v = *(const uint4*)(op + 2 * SZ + i);
    a3.v = *(const uint4*)(op + 3 * SZ + i);
#pragma unroll
    for (int k = 0; k < 8; ++k)
        r.h[k] = f2b(b2f(a0.h[k]) + b2f(a1.h[k]) + b2f(a2.h[k]) + b2f(a3.h[k]));
    *(uint4*)(ab + i) = r.v;
}

// ---------------------------------------------------------------- out-proj (m97-style): (4096x1024)@(1024x1024)^T(+bias)
__global__ void k_outproj(const u16* __restrict__ A, const u16* __restrict__ Bm,
                          const float* __restrict__ bias, void* __restrict__ outv,
                          const int* __restrict__ flag) {
    __shared__ __align__(16) u16 As[128 * 32];
    __shared__ __align__(16) u16 Bs[128 * 32];
    bool f32 = (*flag) != 0;
    int m0 = blockIdx.x * 128, n0 = blockIdx.y * 128;
    int tid = threadIdx.x, lane = tid & 63, wv = tid >> 6;
    int q = lane >> 4, l = lane & 15;
    int wm = (wv >> 1) * 64, wn = (wv & 1) * 64;
    f32x4 acc[4][4] = {};
    int r16 = lane >> 2;
    int ccol = (lane & 3) * 8;
    for (int kc = 0; kc < 1024; kc += 32) {
#pragma unroll
        for (int j = 0; j < 4; ++j) {
            int chunk = wv * 4 + j;
            if (chunk < 8) {
                const u16* g = A + (size_t)(m0 + chunk * 16 + r16) * 1024 + kc + ccol;
                gl_lds16(g, (char*)As + chunk * 1024);
            } else {
                int ch = chunk - 8;
                const u16* g = Bm + (size_t)(n0 + ch * 16 + r16) * 1024 + kc + ccol;
                gl_lds16(g, (char*)Bs + ch * 1024);
            }
        }
        __syncthreads();
        s16x8 af[4], bf[4];
#pragma unroll
        for (int t = 0; t < 4; ++t) {
            af[t] = *(const s16x8*)(As + (wm + t * 16 + l) * 32 + q * 8);
            bf[t] = *(const s16x8*)(Bs + (wn + t * 16 + l) * 32 + q * 8);
        }
#pragma unroll
        for (int i = 0; i < 4; ++i)
#pragma unroll
            for (int j2 = 0; j2 < 4; ++j2)
                acc[i][j2] = mfma_bf16(af[i], bf[j2], acc[i][j2]);
        __syncthreads();
    }
#pragma unroll
    for (int i = 0; i < 4; ++i)
#pragma unroll
        for (int j2 = 0; j2 < 4; ++j2)
#pragma unroll
            for (int r = 0; r < 4; ++r) {
                int row = m0 + wm + i * 16 + q * 4 + r;
                int col = n0 + wn + j2 * 16 + l;
                float val = acc[i][j2][r] + bias[col];
                size_t idx = (size_t)row * E_DIM + col;
                if (f32) ((float*)outv)[idx] = val;
                else     ((u16*)outv)[idx]   = f2b(val);
            }
}

extern "C" void kernel_launch(void* const* d_in, const int* in_sizes, int n_in,
                              void* d_out, int out_size, void* d_ws, size_t ws_size,
                              hipStream_t stream) {
    (void)in_sizes; (void)n_in; (void)out_size; (void)ws_size;
    const void* x      = d_in[0];
    const void* w_qkv  = d_in[1];
    const void* w_pre  = d_in[2];
    const void* w_post = d_in[3];
    const void* w_out  = d_in[4];
    const void* b_out  = d_in[5];

    char* ws = (char*)d_ws;
    size_t off = 0;
    auto alloc = [&](size_t bytes) -> char* {
        char* p = ws + off;
        off += (bytes + 255) & ~(size_t)255;
        return p;
    };
    // region0: xb(8M) | wqkvT(6M) | qkv(24M) early; aliased by opart(32M) late
    char* region0 = alloc((size_t)(8 + 6 + 24) * 1024 * 1024);
    u16*  xb      = (u16*)region0;
    u16*  wqkvT   = (u16*)(region0 + (size_t)8 * 1024 * 1024);
    u16*  qkv     = (u16*)(region0 + (size_t)14 * 1024 * 1024);
    u16*  opart   = (u16*)region0;                              // 4 x 8 MB bf16 partials
    int*  flag    = (int*)alloc(256);
    u16*  woutb   = (u16*)alloc((size_t)1024 * 1024 * 2);
    float* wpre_c = (float*)alloc(256 * 4);
    float* wpost_c= (float*)alloc(256 * 4);
    float* bout_c = (float*)alloc(1024 * 4);
    u16*  qr      = (u16*)alloc((size_t)NB * NH * T_SEQ * HD * 2);
    u16*  kr      = (u16*)alloc((size_t)NB * NH * T_SEQ * HD * 2);
    u16*  vt      = (u16*)alloc((size_t)NB * NH * HD * T_SEQ * 2);
    float* lpart  = (float*)alloc((size_t)8 * NH * T_SEQ * 4);  // [combo][g][t]
    u16*  ab      = (u16*)alloc((size_t)4096 * 1024 * 2);

    k_detect<<<1, 256, 0, stream>>>((const u16*)x, flag);
    k_cvt_bf16<<<16384, 256, 0, stream>>>(x, xb, 4096 * 1024, flag);
    k_cvt_bf16<<<4096, 256, 0, stream>>>(w_out, woutb, 1024 * 1024, flag);
    k_cvt_small<<<6, 256, 0, stream>>>(w_pre, w_post, b_out, wpre_c, wpost_c, bout_c, flag);
    k_transpose<<<dim3(96, 32), 256, 0, stream>>>(w_qkv, wqkvT, flag);
    k_qkv<<<dim3(32, 24), 256, 0, stream>>>(xb, wqkvT, qkv);
    k_rope<<<dim3(32, 16, 2), 256, 0, stream>>>(qkv, qr, kr, vt);
    k_pass1<<<512, 256, 0, stream>>>(qr, kr, wpre_c, lpart);
    k_pass2<<<512, 256, 0, stream>>>(qr, kr, vt, lpart, wpre_c, wpost_c, opart);
    k_sum<<<2048, 256, 0, stream>>>(opart, ab);
    k_outproj<<<dim3(32, 8), 256, 0, stream>>>(ab, woutb, bout_c, d_out, flag);
}